// Round 8
// baseline (221.473 us; speedup 1.0000x reference)
//
#include <hip/hip_runtime.h>
#include <math.h>

#define L_SEQ 4096
#define C_DIM 256
#define H_HEADS 8
#define K_MAX 64
#define D_HEAD 32
#define HALF_W 32
#define N_OFF 65          // 2*HALF_W + 1
#define HK 512            // H_HEADS * K_MAX

__device__ __forceinline__ float sigmoidf_(float x) { return 1.0f / (1.0f + expf(-x)); }

// ================= K1: fused projection GEMM =================
// BM=128, BN=64, BK=16, TM=8, TN=8, 128 threads (2 waves), grid (12, 32) = 384.
// 4 ds_read_b128 per 64 fma (16 fma/read vs 10.7 before) -> LDS-issue relief.
// Per-output sequential-k fmaf chain (k=0..255) => kwbuf/vbuf bitwise identical.
__global__ void proj_gemm(const float* __restrict__ A, const float* __restrict__ kw_w,
                          const float* __restrict__ vw, const float* __restrict__ kb,
                          const float* __restrict__ vb,
                          float* __restrict__ kwbuf, float* __restrict__ vbuf) {
    __shared__ float As[16][132];   // [k][m]
    __shared__ float Bs[16][68];    // [k][n]

    const int tid = threadIdx.x;      // 0..127
    const int tx = tid & 7;           // 0..7  (8 cols each)
    const int ty = tid >> 3;          // 0..15 (8 rows each)
    const int l0 = blockIdx.y * 128;
    const int n0 = blockIdx.x * 64;

    // A: one full row (16 k) per thread = 4 float4
    const int arow = tid;             // 0..127
    // B: 2 float4 per thread
    const int bk = tid >> 3;          // 0..15
    const int bn = (tid & 7) * 8;     // 0..56

    const float* Bsrc;
    int ldb, coff;
    if (n0 < 512) { Bsrc = kw_w; ldb = 512; coff = n0; }
    else          { Bsrc = vw;   ldb = 256; coff = n0 - 512; }

    float acc[8][8];
#pragma unroll
    for (int i = 0; i < 8; ++i)
#pragma unroll
        for (int jj = 0; jj < 8; ++jj) acc[i][jj] = 0.0f;

    const float* arow_p = A + (l0 + arow) * C_DIM;
    float4 a0 = *(const float4*)&arow_p[0];
    float4 a1 = *(const float4*)&arow_p[4];
    float4 a2 = *(const float4*)&arow_p[8];
    float4 a3 = *(const float4*)&arow_p[12];
    float4 b0 = *(const float4*)&Bsrc[bk * ldb + coff + bn];
    float4 b1 = *(const float4*)&Bsrc[bk * ldb + coff + bn + 4];

    for (int k0 = 0; k0 < C_DIM; k0 += 16) {
        __syncthreads();
        As[0][arow]  = a0.x; As[1][arow]  = a0.y; As[2][arow]  = a0.z; As[3][arow]  = a0.w;
        As[4][arow]  = a1.x; As[5][arow]  = a1.y; As[6][arow]  = a1.z; As[7][arow]  = a1.w;
        As[8][arow]  = a2.x; As[9][arow]  = a2.y; As[10][arow] = a2.z; As[11][arow] = a2.w;
        As[12][arow] = a3.x; As[13][arow] = a3.y; As[14][arow] = a3.z; As[15][arow] = a3.w;
        *(float4*)&Bs[bk][bn]     = b0;
        *(float4*)&Bs[bk][bn + 4] = b1;
        __syncthreads();
        if (k0 + 16 < C_DIM) {
            a0 = *(const float4*)&arow_p[k0 + 16 + 0];
            a1 = *(const float4*)&arow_p[k0 + 16 + 4];
            a2 = *(const float4*)&arow_p[k0 + 16 + 8];
            a3 = *(const float4*)&arow_p[k0 + 16 + 12];
            b0 = *(const float4*)&Bsrc[(k0 + 16 + bk) * ldb + coff + bn];
            b1 = *(const float4*)&Bsrc[(k0 + 16 + bk) * ldb + coff + bn + 4];
        }
#pragma unroll
        for (int kk = 0; kk < 16; ++kk) {
            const float4 alo = *(const float4*)&As[kk][ty * 8];
            const float4 ahi = *(const float4*)&As[kk][ty * 8 + 4];
            const float4 blo = *(const float4*)&Bs[kk][tx * 8];
            const float4 bhi = *(const float4*)&Bs[kk][tx * 8 + 4];
            const float ar[8] = {alo.x, alo.y, alo.z, alo.w, ahi.x, ahi.y, ahi.z, ahi.w};
            const float br[8] = {blo.x, blo.y, blo.z, blo.w, bhi.x, bhi.y, bhi.z, bhi.w};
#pragma unroll
            for (int i = 0; i < 8; ++i)
#pragma unroll
                for (int jj = 0; jj < 8; ++jj)
                    acc[i][jj] = fmaf(ar[i], br[jj], acc[i][jj]);
        }
    }

    const int g0 = n0 + tx * 8;
    float4 bz0, bz1;
    float* dst;
    int stride, col;
    if (g0 < 512) {
        bz0 = *(const float4*)&kb[g0]; bz1 = *(const float4*)&kb[g0 + 4];
        dst = kwbuf; stride = 512; col = g0;
    } else {
        bz0 = *(const float4*)&vb[g0 - 512]; bz1 = *(const float4*)&vb[g0 - 508];
        dst = vbuf; stride = 256; col = g0 - 512;
    }
#pragma unroll
    for (int i = 0; i < 8; ++i) {
        const int row = l0 + ty * 8 + i;
        float4 o0, o1;
        o0.x = acc[i][0] + bz0.x; o0.y = acc[i][1] + bz0.y;
        o0.z = acc[i][2] + bz0.z; o0.w = acc[i][3] + bz0.w;
        o1.x = acc[i][4] + bz1.x; o1.y = acc[i][5] + bz1.y;
        o1.z = acc[i][6] + bz1.z; o1.w = acc[i][7] + bz1.w;
        *(float4*)&dst[row * stride + col]     = o0;
        *(float4*)&dst[row * stride + col + 4] = o1;
    }
}

// ================= K2: fused norm + small-proj + adaptive local conv =================
// 512 threads. Phase A (waves 0-3, bitwise tree) runs concurrently with Phase B
// (wave 4, bitwise small-proj). Stage 3: 1 head/wave, 2 rows/iter, shfl reduce
// (regroups only the non-chaotic conv output sum).
__global__ void conv_fused(const float* __restrict__ x,
                           const float* __restrict__ ww, const float* __restrict__ wb,
                           const float* __restrict__ wg,
                           const float* __restrict__ ow, const float* __restrict__ ob,
                           const float* __restrict__ og,
                           const float* __restrict__ kg,
                           const float* __restrict__ kwraw, const float* __restrict__ v,
                           float* __restrict__ out) {
    const int l = blockIdx.x;
    const int tid = threadIdx.x;   // 0..511

    __shared__ float red[256];
    __shared__ float rs_s;
    __shared__ float kwrow[HK];
    __shared__ float wsz[H_HEADS], ofs[H_HEADS];
    __shared__ float4 tap[H_HEADS][N_OFF];      // {attn, frac, as_float(offF), as_float(offC)}
    __shared__ float2 warr[H_HEADS][N_OFF + 1]; // {combined weight, as_float(rowoff)}
    __shared__ float inv_denom[H_HEADS];
    __shared__ int okflag;

    // ---- Segment 1: phase A part 1 (waves 0-3) || phase B (wave 4) ----
    float z0 = 0.0f, z1 = 0.0f;
    if (tid < 256) {
        const float* row = kwraw + l * HK;
        z0 = row[tid];
        z1 = row[tid + 256];
        red[tid] = z0 * z0 + z1 * z1;
    } else if (tid < 320) {
        // Phase B: small projections — bitwise == round 7 (wave-local, lane = tid-256)
        const int lane = tid - 256;
        const float* xr = x + l * C_DIM;
        float accw[H_HEADS], acco[H_HEADS];
#pragma unroll
        for (int h = 0; h < H_HEADS; ++h) { accw[h] = 0.0f; acco[h] = 0.0f; }
#pragma unroll
        for (int i = 0; i < C_DIM / 64; ++i) {
            const int c = lane + i * 64;
            const float xv = xr[c];
            const float* wwc = ww + c * H_HEADS;
            const float* owc = ow + c * H_HEADS;
#pragma unroll
            for (int h = 0; h < H_HEADS; ++h) {
                accw[h] = fmaf(xv, wwc[h], accw[h]);
                acco[h] = fmaf(xv, owc[h], acco[h]);
            }
        }
#pragma unroll
        for (int off = 32; off > 0; off >>= 1) {
#pragma unroll
            for (int h = 0; h < H_HEADS; ++h) {
                accw[h] += __shfl_xor(accw[h], off);
                acco[h] += __shfl_xor(acco[h], off);
            }
        }
        if (lane < H_HEADS) {
            float zw[H_HEADS], zo[H_HEADS];
            float ssw = 0.0f, sso = 0.0f;
#pragma unroll
            for (int h = 0; h < H_HEADS; ++h) {
                zw[h] = accw[h] + wb[h];
                zo[h] = acco[h] + ob[h];
                ssw += zw[h] * zw[h];
                sso += zo[h] * zo[h];
            }
            const float rw = rsqrtf(ssw / (float)H_HEADS + 1e-6f);
            const float ro = rsqrtf(sso / (float)H_HEADS + 1e-6f);
            const float nw = wg[lane] * zw[lane] * rw;
            const float no = og[lane] * zo[lane] * ro;
            wsz[lane] = 1.0f + sigmoidf_(nw) * 63.0f;
            ofs[lane] = tanhf(no) * 64.0f;
        }
    }
    if (tid == 0) okflag = 1;
    __syncthreads();

    // ---- Phase A tree: s=128 (cross-wave), then wave-0-internal s=64..1 ----
    if (tid < 128) red[tid] += red[tid + 128];
    __syncthreads();
    if (tid < 64) {
        red[tid] += red[tid + 64];                  // s=64: all wave-0 lanes
        if (tid < 32) red[tid] += red[tid + 32];    // s<=32: wave-0 internal, program order
        if (tid < 16) red[tid] += red[tid + 16];
        if (tid < 8)  red[tid] += red[tid + 8];
        if (tid < 4)  red[tid] += red[tid + 4];
        if (tid < 2)  red[tid] += red[tid + 2];
        if (tid < 1) {
            red[0] += red[1];
            rs_s = rsqrtf(red[0] / (float)HK + 1e-6f);
        }
    }
    __syncthreads();
    if (tid < 256) {
        const float rs = rs_s;
        const float n0v = kg[tid] * z0 * rs;
        const float n1v = kg[tid + 256] * z1 * rs;
        kwrow[tid]       = n0v * sigmoidf_(n0v);
        kwrow[tid + 256] = n1v * sigmoidf_(n1v);
    }
    __syncthreads();

    // ---- Stage 1: attention taps (expressions bitwise == round 7) ----
    for (int t = tid; t < H_HEADS * N_OFF; t += 512) {
        const int h = t / N_OFF;
        const int n = t - h * N_OFF;
        const float ws  = wsz[h];
        const float off = ofs[h];
        const float local = (float)(n - HALF_W);
        const float neighbor = (float)l + off + local;
        const bool valid = (neighbor >= 0.0f) && (neighbor < (float)L_SEQ);
        const float nc = fminf(fmaxf(neighbor, 0.0f), (float)(L_SEQ - 1));

        const float rel = fabsf(local) / (ws * 0.5f + 1e-6f);
        const float mask = sigmoidf_(5.0f * (1.0f - rel)) * (valid ? 1.0f : 0.0f);

        const float kidx = fminf(rel, 1.0f) * (float)(K_MAX - 1);
        int ifl = (int)kidx;
        ifl = min(ifl, K_MAX - 2);
        const float wce = kidx - (float)ifl;
        const float kf = kwrow[h * K_MAX + ifl];
        const float kc = kwrow[h * K_MAX + ifl + 1];
        const float attnv = (kf * (1.0f - wce) + kc * wce) * mask;

        int p = (int)floorf(nc);
        p = min(max(p, 0), L_SEQ - 1);
        const int pc = min(p + 1, L_SEQ - 1);
        const float fr = nc - (float)p;

        float4 tv;
        tv.x = attnv;
        tv.y = fr;
        tv.z = __int_as_float(p * C_DIM + h * D_HEAD);
        tv.w = __int_as_float(pc * C_DIM + h * D_HEAD);
        tap[h][n] = tv;
    }
    __syncthreads();

    // ---- Stage 1.5: combined row weights + fast-path validity ----
    for (int t = tid; t < H_HEADS * (N_OFF + 1); t += 512) {
        const int h = t / (N_OFF + 1);
        const int m = t - h * (N_OFF + 1);
        float w, rowf;
        if (m == 0) {
            const float4 cur = tap[h][0];
            w = cur.x * (1.0f - cur.y);
            rowf = cur.z;
        } else {
            const float4 prev = tap[h][m - 1];
            const float wc = prev.x * prev.y;
            if (m < N_OFF) {
                const float4 cur = tap[h][m];
                w = cur.x * (1.0f - cur.y) + wc;
                rowf = cur.z;
                if (wc != 0.0f && __float_as_int(prev.w) != __float_as_int(cur.z))
                    okflag = 0;   // benign race: all writers store 0
            } else {
                w = wc;
                rowf = prev.w;
            }
        }
        warr[h][m] = make_float2(w, rowf);
    }

    // ---- Stage 2: per-head denominators (serial n order, bitwise == round 7) ----
    if (tid < H_HEADS) {
        float s = 0.0f;
        for (int n = 0; n < N_OFF; ++n) s += tap[tid][n].x;
        inv_denom[tid] = 1.0f / (s + 1e-6f);
    }
    __syncthreads();

    // ---- Stage 3: one head per wave, 2 rows per iteration ----
    const int h = tid >> 6;          // wave id = head
    const int lane = tid & 63;
    const int half = lane >> 5;      // 0: even rows, 1: odd rows
    const int d = lane & 31;
    float acc = 0.0f;
    if (okflag) {
#pragma unroll 3
        for (int it = 0; it < (N_OFF + 1) / 2; ++it) {       // 33 iters, m = 2*it+half
            const float2 t2 = warr[h][2 * it + half];
            acc = fmaf(t2.x, v[__float_as_int(t2.y) + d], acc);
        }
    } else {
        // slow path: taps split even/odd across halves
#pragma unroll 3
        for (int it = 0; it < 33; ++it) {
            const int n = 2 * it + half;
            if (n < N_OFF) {
                const float4 t4 = tap[h][n];
                const float vf = v[__float_as_int(t4.z) + d];
                const float vc = v[__float_as_int(t4.w) + d];
                acc = fmaf(t4.x, fmaf(t4.y, vc - vf, vf), acc);
            }
        }
    }
    acc += __shfl_xor(acc, 32);
    if (half == 0) out[l * C_DIM + h * D_HEAD + d] = acc * inv_denom[h];
}

// ================= K3: out projection GEMM + silu (unchanged from round 7) =================
// BM=64, BN=64, BK=16, TM=4, TN=4, 256 threads, grid (4, 64) = 256 blocks.
__global__ void out_gemm(const float* __restrict__ A, const float* __restrict__ W,
                         float* __restrict__ out) {
    __shared__ float As[16][68];
    __shared__ float Bs[16][68];

    const int tid = threadIdx.x;
    const int tx = tid & 15;
    const int ty = tid >> 4;
    const int l0 = blockIdx.y * 64;
    const int n0 = blockIdx.x * 64;

    const int am = tid >> 2;
    const int ak = (tid & 3) * 4;
    const int bk = tid >> 4;
    const int bn = (tid & 15) * 4;

    float acc[4][4];
#pragma unroll
    for (int i = 0; i < 4; ++i)
#pragma unroll
        for (int jj = 0; jj < 4; ++jj) acc[i][jj] = 0.0f;

    float4 av = *(const float4*)&A[(l0 + am) * C_DIM + ak];
    float4 bv = *(const float4*)&W[bk * C_DIM + n0 + bn];

    for (int k0 = 0; k0 < C_DIM; k0 += 16) {
        __syncthreads();
        As[ak + 0][am] = av.x;
        As[ak + 1][am] = av.y;
        As[ak + 2][am] = av.z;
        As[ak + 3][am] = av.w;
        *(float4*)&Bs[bk][bn] = bv;
        __syncthreads();
        if (k0 + 16 < C_DIM) {
            av = *(const float4*)&A[(l0 + am) * C_DIM + (k0 + 16) + ak];
            bv = *(const float4*)&W[(k0 + 16 + bk) * C_DIM + n0 + bn];
        }
#pragma unroll
        for (int kk = 0; kk < 16; ++kk) {
            const float4 a4 = *(const float4*)&As[kk][ty * 4];
            const float4 b4 = *(const float4*)&Bs[kk][tx * 4];
            const float ar[4] = {a4.x, a4.y, a4.z, a4.w};
            const float br[4] = {b4.x, b4.y, b4.z, b4.w};
#pragma unroll
            for (int i = 0; i < 4; ++i)
#pragma unroll
                for (int jj = 0; jj < 4; ++jj)
                    acc[i][jj] = fmaf(ar[i], br[jj], acc[i][jj]);
        }
    }

    const int g0 = n0 + tx * 4;
#pragma unroll
    for (int i = 0; i < 4; ++i) {
        const int row = l0 + ty * 4 + i;
        float4 o;
        o.x = acc[i][0] * sigmoidf_(acc[i][0]);
        o.y = acc[i][1] * sigmoidf_(acc[i][1]);
        o.z = acc[i][2] * sigmoidf_(acc[i][2]);
        o.w = acc[i][3] * sigmoidf_(acc[i][3]);
        *(float4*)&out[row * C_DIM + g0] = o;
    }
}

extern "C" void kernel_launch(void* const* d_in, const int* in_sizes, int n_in,
                              void* d_out, int out_size, void* d_ws, size_t ws_size,
                              hipStream_t stream) {
    const float* x    = (const float*)d_in[0];
    const float* ww   = (const float*)d_in[1];
    const float* wb   = (const float*)d_in[2];
    const float* wg   = (const float*)d_in[3];
    const float* ow   = (const float*)d_in[4];
    const float* ob   = (const float*)d_in[5];
    const float* og   = (const float*)d_in[6];
    const float* kw_w = (const float*)d_in[7];
    const float* kb   = (const float*)d_in[8];
    const float* kg   = (const float*)d_in[9];
    const float* vw   = (const float*)d_in[10];
    const float* vb   = (const float*)d_in[11];
    const float* outw = (const float*)d_in[12];
    float* y = (float*)d_out;

    float* ws_f    = (float*)d_ws;
    float* kwbuf   = ws_f;                       // 4096*512 (raw z+bias)
    float* vbuf    = kwbuf + L_SEQ * HK;         // 4096*256
    float* convbuf = vbuf + L_SEQ * C_DIM;       // 4096*256

    proj_gemm<<<dim3(12, L_SEQ / 128), 128, 0, stream>>>(x, kw_w, vw, kb, vb, kwbuf, vbuf);
    conv_fused<<<L_SEQ, 512, 0, stream>>>(x, ww, wb, wg, ow, ob, og, kg, kwbuf, vbuf, convbuf);
    out_gemm<<<dim3(C_DIM / 64, L_SEQ / 64), 256, 0, stream>>>(convbuf, outw, y);
}

// Round 9
// 184.533 us; speedup vs baseline: 1.2002x; 1.2002x over previous
//
#include <hip/hip_runtime.h>
#include <math.h>

#define L_SEQ 4096
#define C_DIM 256
#define H_HEADS 8
#define K_MAX 64
#define D_HEAD 32
#define HALF_W 32
#define N_OFF 65          // 2*HALF_W + 1
#define HK 512            // H_HEADS * K_MAX

__device__ __forceinline__ float sigmoidf_(float x) { return 1.0f / (1.0f + expf(-x)); }

// ================= K1: fused projection GEMM =================
// BM=128, BN=64, BK=16, TM=8, TN=8, 128 threads (2 waves), grid (12, 32) = 384.
// __launch_bounds__(128,2): VGPR ceiling 256 -> 64-reg accumulator fits, NO SPILL
// (round-8 failure: default 1024-thread assumption capped VGPR at 64 -> scratch).
__global__ void __launch_bounds__(128, 2)
proj_gemm(const float* __restrict__ A, const float* __restrict__ kw_w,
          const float* __restrict__ vw, const float* __restrict__ kb,
          const float* __restrict__ vb,
          float* __restrict__ kwbuf, float* __restrict__ vbuf) {
    __shared__ float As[16][132];   // [k][m]
    __shared__ float Bs[16][68];    // [k][n]

    const int tid = threadIdx.x;      // 0..127
    const int tx = tid & 7;           // 0..7  (8 cols each)
    const int ty = tid >> 3;          // 0..15 (8 rows each)
    const int l0 = blockIdx.y * 128;
    const int n0 = blockIdx.x * 64;

    const int arow = tid;             // 0..127 (one full row of 16 k per thread)
    const int bk = tid >> 3;          // 0..15
    const int bn = (tid & 7) * 8;     // 0..56

    const float* Bsrc;
    int ldb, coff;
    if (n0 < 512) { Bsrc = kw_w; ldb = 512; coff = n0; }
    else          { Bsrc = vw;   ldb = 256; coff = n0 - 512; }

    float acc[8][8];
#pragma unroll
    for (int i = 0; i < 8; ++i)
#pragma unroll
        for (int jj = 0; jj < 8; ++jj) acc[i][jj] = 0.0f;

    const float* arow_p = A + (l0 + arow) * C_DIM;
    float4 a0 = *(const float4*)&arow_p[0];
    float4 a1 = *(const float4*)&arow_p[4];
    float4 a2 = *(const float4*)&arow_p[8];
    float4 a3 = *(const float4*)&arow_p[12];
    float4 b0 = *(const float4*)&Bsrc[bk * ldb + coff + bn];
    float4 b1 = *(const float4*)&Bsrc[bk * ldb + coff + bn + 4];

    for (int k0 = 0; k0 < C_DIM; k0 += 16) {
        __syncthreads();
        As[0][arow]  = a0.x; As[1][arow]  = a0.y; As[2][arow]  = a0.z; As[3][arow]  = a0.w;
        As[4][arow]  = a1.x; As[5][arow]  = a1.y; As[6][arow]  = a1.z; As[7][arow]  = a1.w;
        As[8][arow]  = a2.x; As[9][arow]  = a2.y; As[10][arow] = a2.z; As[11][arow] = a2.w;
        As[12][arow] = a3.x; As[13][arow] = a3.y; As[14][arow] = a3.z; As[15][arow] = a3.w;
        *(float4*)&Bs[bk][bn]     = b0;
        *(float4*)&Bs[bk][bn + 4] = b1;
        __syncthreads();
        if (k0 + 16 < C_DIM) {
            a0 = *(const float4*)&arow_p[k0 + 16 + 0];
            a1 = *(const float4*)&arow_p[k0 + 16 + 4];
            a2 = *(const float4*)&arow_p[k0 + 16 + 8];
            a3 = *(const float4*)&arow_p[k0 + 16 + 12];
            b0 = *(const float4*)&Bsrc[(k0 + 16 + bk) * ldb + coff + bn];
            b1 = *(const float4*)&Bsrc[(k0 + 16 + bk) * ldb + coff + bn + 4];
        }
#pragma unroll
        for (int kk = 0; kk < 16; ++kk) {
            const float4 alo = *(const float4*)&As[kk][ty * 8];
            const float4 ahi = *(const float4*)&As[kk][ty * 8 + 4];
            const float4 blo = *(const float4*)&Bs[kk][tx * 8];
            const float4 bhi = *(const float4*)&Bs[kk][tx * 8 + 4];
            const float ar[8] = {alo.x, alo.y, alo.z, alo.w, ahi.x, ahi.y, ahi.z, ahi.w};
            const float br[8] = {blo.x, blo.y, blo.z, blo.w, bhi.x, bhi.y, bhi.z, bhi.w};
#pragma unroll
            for (int i = 0; i < 8; ++i)
#pragma unroll
                for (int jj = 0; jj < 8; ++jj)
                    acc[i][jj] = fmaf(ar[i], br[jj], acc[i][jj]);
        }
    }

    const int g0 = n0 + tx * 8;
    float4 bz0, bz1;
    float* dst;
    int stride, col;
    if (g0 < 512) {
        bz0 = *(const float4*)&kb[g0]; bz1 = *(const float4*)&kb[g0 + 4];
        dst = kwbuf; stride = 512; col = g0;
    } else {
        bz0 = *(const float4*)&vb[g0 - 512]; bz1 = *(const float4*)&vb[g0 - 508];
        dst = vbuf; stride = 256; col = g0 - 512;
    }
#pragma unroll
    for (int i = 0; i < 8; ++i) {
        const int row = l0 + ty * 8 + i;
        float4 o0, o1;
        o0.x = acc[i][0] + bz0.x; o0.y = acc[i][1] + bz0.y;
        o0.z = acc[i][2] + bz0.z; o0.w = acc[i][3] + bz0.w;
        o1.x = acc[i][4] + bz1.x; o1.y = acc[i][5] + bz1.y;
        o1.z = acc[i][6] + bz1.z; o1.w = acc[i][7] + bz1.w;
        *(float4*)&dst[row * stride + col]     = o0;
        *(float4*)&dst[row * stride + col + 4] = o1;
    }
}

// ================= K2: fused norm + small-proj + adaptive local conv =================
// 512 threads (unchanged from round 8 except launch bounds).
__global__ void __launch_bounds__(512, 1)
conv_fused(const float* __restrict__ x,
           const float* __restrict__ ww, const float* __restrict__ wb,
           const float* __restrict__ wg,
           const float* __restrict__ ow, const float* __restrict__ ob,
           const float* __restrict__ og,
           const float* __restrict__ kg,
           const float* __restrict__ kwraw, const float* __restrict__ v,
           float* __restrict__ out) {
    const int l = blockIdx.x;
    const int tid = threadIdx.x;   // 0..511

    __shared__ float red[256];
    __shared__ float rs_s;
    __shared__ float kwrow[HK];
    __shared__ float wsz[H_HEADS], ofs[H_HEADS];
    __shared__ float4 tap[H_HEADS][N_OFF];      // {attn, frac, as_float(offF), as_float(offC)}
    __shared__ float2 warr[H_HEADS][N_OFF + 1]; // {combined weight, as_float(rowoff)}
    __shared__ float inv_denom[H_HEADS];
    __shared__ int okflag;

    // ---- Segment 1: phase A part 1 (waves 0-3) || phase B (wave 4) ----
    float z0 = 0.0f, z1 = 0.0f;
    if (tid < 256) {
        const float* row = kwraw + l * HK;
        z0 = row[tid];
        z1 = row[tid + 256];
        red[tid] = z0 * z0 + z1 * z1;
    } else if (tid < 320) {
        const int lane = tid - 256;
        const float* xr = x + l * C_DIM;
        float accw[H_HEADS], acco[H_HEADS];
#pragma unroll
        for (int h = 0; h < H_HEADS; ++h) { accw[h] = 0.0f; acco[h] = 0.0f; }
#pragma unroll
        for (int i = 0; i < C_DIM / 64; ++i) {
            const int c = lane + i * 64;
            const float xv = xr[c];
            const float* wwc = ww + c * H_HEADS;
            const float* owc = ow + c * H_HEADS;
#pragma unroll
            for (int h = 0; h < H_HEADS; ++h) {
                accw[h] = fmaf(xv, wwc[h], accw[h]);
                acco[h] = fmaf(xv, owc[h], acco[h]);
            }
        }
#pragma unroll
        for (int off = 32; off > 0; off >>= 1) {
#pragma unroll
            for (int h = 0; h < H_HEADS; ++h) {
                accw[h] += __shfl_xor(accw[h], off);
                acco[h] += __shfl_xor(acco[h], off);
            }
        }
        if (lane < H_HEADS) {
            float zw[H_HEADS], zo[H_HEADS];
            float ssw = 0.0f, sso = 0.0f;
#pragma unroll
            for (int h = 0; h < H_HEADS; ++h) {
                zw[h] = accw[h] + wb[h];
                zo[h] = acco[h] + ob[h];
                ssw += zw[h] * zw[h];
                sso += zo[h] * zo[h];
            }
            const float rw = rsqrtf(ssw / (float)H_HEADS + 1e-6f);
            const float ro = rsqrtf(sso / (float)H_HEADS + 1e-6f);
            const float nw = wg[lane] * zw[lane] * rw;
            const float no = og[lane] * zo[lane] * ro;
            wsz[lane] = 1.0f + sigmoidf_(nw) * 63.0f;
            ofs[lane] = tanhf(no) * 64.0f;
        }
    }
    if (tid == 0) okflag = 1;
    __syncthreads();

    // ---- Phase A tree: s=128 (cross-wave), then wave-0-internal s=64..1 ----
    if (tid < 128) red[tid] += red[tid + 128];
    __syncthreads();
    if (tid < 64) {
        red[tid] += red[tid + 64];
        if (tid < 32) red[tid] += red[tid + 32];
        if (tid < 16) red[tid] += red[tid + 16];
        if (tid < 8)  red[tid] += red[tid + 8];
        if (tid < 4)  red[tid] += red[tid + 4];
        if (tid < 2)  red[tid] += red[tid + 2];
        if (tid < 1) {
            red[0] += red[1];
            rs_s = rsqrtf(red[0] / (float)HK + 1e-6f);
        }
    }
    __syncthreads();
    if (tid < 256) {
        const float rs = rs_s;
        const float n0v = kg[tid] * z0 * rs;
        const float n1v = kg[tid + 256] * z1 * rs;
        kwrow[tid]       = n0v * sigmoidf_(n0v);
        kwrow[tid + 256] = n1v * sigmoidf_(n1v);
    }
    __syncthreads();

    // ---- Stage 1: attention taps ----
    for (int t = tid; t < H_HEADS * N_OFF; t += 512) {
        const int h = t / N_OFF;
        const int n = t - h * N_OFF;
        const float ws  = wsz[h];
        const float off = ofs[h];
        const float local = (float)(n - HALF_W);
        const float neighbor = (float)l + off + local;
        const bool valid = (neighbor >= 0.0f) && (neighbor < (float)L_SEQ);
        const float nc = fminf(fmaxf(neighbor, 0.0f), (float)(L_SEQ - 1));

        const float rel = fabsf(local) / (ws * 0.5f + 1e-6f);
        const float mask = sigmoidf_(5.0f * (1.0f - rel)) * (valid ? 1.0f : 0.0f);

        const float kidx = fminf(rel, 1.0f) * (float)(K_MAX - 1);
        int ifl = (int)kidx;
        ifl = min(ifl, K_MAX - 2);
        const float wce = kidx - (float)ifl;
        const float kf = kwrow[h * K_MAX + ifl];
        const float kc = kwrow[h * K_MAX + ifl + 1];
        const float attnv = (kf * (1.0f - wce) + kc * wce) * mask;

        int p = (int)floorf(nc);
        p = min(max(p, 0), L_SEQ - 1);
        const int pc = min(p + 1, L_SEQ - 1);
        const float fr = nc - (float)p;

        float4 tv;
        tv.x = attnv;
        tv.y = fr;
        tv.z = __int_as_float(p * C_DIM + h * D_HEAD);
        tv.w = __int_as_float(pc * C_DIM + h * D_HEAD);
        tap[h][n] = tv;
    }
    __syncthreads();

    // ---- Stage 1.5: combined row weights + fast-path validity ----
    for (int t = tid; t < H_HEADS * (N_OFF + 1); t += 512) {
        const int h = t / (N_OFF + 1);
        const int m = t - h * (N_OFF + 1);
        float w, rowf;
        if (m == 0) {
            const float4 cur = tap[h][0];
            w = cur.x * (1.0f - cur.y);
            rowf = cur.z;
        } else {
            const float4 prev = tap[h][m - 1];
            const float wc = prev.x * prev.y;
            if (m < N_OFF) {
                const float4 cur = tap[h][m];
                w = cur.x * (1.0f - cur.y) + wc;
                rowf = cur.z;
                if (wc != 0.0f && __float_as_int(prev.w) != __float_as_int(cur.z))
                    okflag = 0;   // benign race: all writers store 0
            } else {
                w = wc;
                rowf = prev.w;
            }
        }
        warr[h][m] = make_float2(w, rowf);
    }

    // ---- Stage 2: per-head denominators ----
    if (tid < H_HEADS) {
        float s = 0.0f;
        for (int n = 0; n < N_OFF; ++n) s += tap[tid][n].x;
        inv_denom[tid] = 1.0f / (s + 1e-6f);
    }
    __syncthreads();

    // ---- Stage 3: one head per wave, 2 rows per iteration ----
    const int h = tid >> 6;
    const int lane = tid & 63;
    const int half = lane >> 5;
    const int d = lane & 31;
    float acc = 0.0f;
    if (okflag) {
#pragma unroll 3
        for (int it = 0; it < (N_OFF + 1) / 2; ++it) {
            const float2 t2 = warr[h][2 * it + half];
            acc = fmaf(t2.x, v[__float_as_int(t2.y) + d], acc);
        }
    } else {
#pragma unroll 3
        for (int it = 0; it < 33; ++it) {
            const int n = 2 * it + half;
            if (n < N_OFF) {
                const float4 t4 = tap[h][n];
                const float vf = v[__float_as_int(t4.z) + d];
                const float vc = v[__float_as_int(t4.w) + d];
                acc = fmaf(t4.x, fmaf(t4.y, vc - vf, vf), acc);
            }
        }
    }
    acc += __shfl_xor(acc, 32);
    if (half == 0) out[l * C_DIM + h * D_HEAD + d] = acc * inv_denom[h];
}

// ================= K3: out projection GEMM + silu =================
// BM=64, BN=64, BK=16, TM=4, TN=4, 256 threads, grid (4, 64) = 256 blocks.
__global__ void __launch_bounds__(256, 4)
out_gemm(const float* __restrict__ A, const float* __restrict__ W,
         float* __restrict__ out) {
    __shared__ float As[16][68];
    __shared__ float Bs[16][68];

    const int tid = threadIdx.x;
    const int tx = tid & 15;
    const int ty = tid >> 4;
    const int l0 = blockIdx.y * 64;
    const int n0 = blockIdx.x * 64;

    const int am = tid >> 2;
    const int ak = (tid & 3) * 4;
    const int bk = tid >> 4;
    const int bn = (tid & 15) * 4;

    float acc[4][4];
#pragma unroll
    for (int i = 0; i < 4; ++i)
#pragma unroll
        for (int jj = 0; jj < 4; ++jj) acc[i][jj] = 0.0f;

    float4 av = *(const float4*)&A[(l0 + am) * C_DIM + ak];
    float4 bv = *(const float4*)&W[bk * C_DIM + n0 + bn];

    for (int k0 = 0; k0 < C_DIM; k0 += 16) {
        __syncthreads();
        As[ak + 0][am] = av.x;
        As[ak + 1][am] = av.y;
        As[ak + 2][am] = av.z;
        As[ak + 3][am] = av.w;
        *(float4*)&Bs[bk][bn] = bv;
        __syncthreads();
        if (k0 + 16 < C_DIM) {
            av = *(const float4*)&A[(l0 + am) * C_DIM + (k0 + 16) + ak];
            bv = *(const float4*)&W[(k0 + 16 + bk) * C_DIM + n0 + bn];
        }
#pragma unroll
        for (int kk = 0; kk < 16; ++kk) {
            const float4 a4 = *(const float4*)&As[kk][ty * 4];
            const float4 b4 = *(const float4*)&Bs[kk][tx * 4];
            const float ar[4] = {a4.x, a4.y, a4.z, a4.w};
            const float br[4] = {b4.x, b4.y, b4.z, b4.w};
#pragma unroll
            for (int i = 0; i < 4; ++i)
#pragma unroll
                for (int jj = 0; jj < 4; ++jj)
                    acc[i][jj] = fmaf(ar[i], br[jj], acc[i][jj]);
        }
    }

    const int g0 = n0 + tx * 4;
#pragma unroll
    for (int i = 0; i < 4; ++i) {
        const int row = l0 + ty * 4 + i;
        float4 o;
        o.x = acc[i][0] * sigmoidf_(acc[i][0]);
        o.y = acc[i][1] * sigmoidf_(acc[i][1]);
        o.z = acc[i][2] * sigmoidf_(acc[i][2]);
        o.w = acc[i][3] * sigmoidf_(acc[i][3]);
        *(float4*)&out[row * C_DIM + g0] = o;
    }
}

extern "C" void kernel_launch(void* const* d_in, const int* in_sizes, int n_in,
                              void* d_out, int out_size, void* d_ws, size_t ws_size,
                              hipStream_t stream) {
    const float* x    = (const float*)d_in[0];
    const float* ww   = (const float*)d_in[1];
    const float* wb   = (const float*)d_in[2];
    const float* wg   = (const float*)d_in[3];
    const float* ow   = (const float*)d_in[4];
    const float* ob   = (const float*)d_in[5];
    const float* og   = (const float*)d_in[6];
    const float* kw_w = (const float*)d_in[7];
    const float* kb   = (const float*)d_in[8];
    const float* kg   = (const float*)d_in[9];
    const float* vw   = (const float*)d_in[10];
    const float* vb   = (const float*)d_in[11];
    const float* outw = (const float*)d_in[12];
    float* y = (float*)d_out;

    float* ws_f    = (float*)d_ws;
    float* kwbuf   = ws_f;                       // 4096*512 (raw z+bias)
    float* vbuf    = kwbuf + L_SEQ * HK;         // 4096*256
    float* convbuf = vbuf + L_SEQ * C_DIM;       // 4096*256

    proj_gemm<<<dim3(12, L_SEQ / 128), 128, 0, stream>>>(x, kw_w, vw, kb, vb, kwbuf, vbuf);
    conv_fused<<<L_SEQ, 512, 0, stream>>>(x, ww, wb, wg, ow, ob, og, kg, kwbuf, vbuf, convbuf);
    out_gemm<<<dim3(C_DIM / 64, L_SEQ / 64), 256, 0, stream>>>(convbuf, outw, y);
}

// Round 10
// 149.428 us; speedup vs baseline: 1.4821x; 1.2349x over previous
//
#include <hip/hip_runtime.h>
#include <math.h>

#define L_SEQ 4096
#define C_DIM 256
#define H_HEADS 8
#define K_MAX 64
#define D_HEAD 32
#define HALF_W 32
#define N_OFF 65          // 2*HALF_W + 1
#define HK 512            // H_HEADS * K_MAX

__device__ __forceinline__ float sigmoidf_(float x) { return 1.0f / (1.0f + expf(-x)); }

// ================= K1: fused projection GEMM =================
// BM=128, BN=64, BK=16, TM=8, TN=4, 256 threads (4 waves), grid (12, 32) = 384.
// __launch_bounds__(256,2): VGPR cap 256 >> ~80 needed -> no spill (R8/R9 lesson:
// without bounds hipcc assumes 1024-thr blocks and caps VGPR at 64 -> scratch).
__global__ void __launch_bounds__(256, 2)
proj_gemm(const float* __restrict__ A, const float* __restrict__ kw_w,
          const float* __restrict__ vw, const float* __restrict__ kb,
          const float* __restrict__ vb,
          float* __restrict__ kwbuf, float* __restrict__ vbuf) {
    __shared__ float As[16][132];
    __shared__ float Bs[16][68];

    const int tid = threadIdx.x;
    const int tx = tid & 15;
    const int ty = tid >> 4;
    const int l0 = blockIdx.y * 128;
    const int n0 = blockIdx.x * 64;

    const int ar0 = tid >> 2;
    const int ac0 = (tid & 3) * 4;
    const int ar1 = ar0 + 64;
    const int bk = tid >> 4;
    const int bn = (tid & 15) * 4;

    const float* Bsrc;
    int ldb, coff;
    if (n0 < 512) { Bsrc = kw_w; ldb = 512; coff = n0; }
    else          { Bsrc = vw;   ldb = 256; coff = n0 - 512; }

    float acc[8][4];
#pragma unroll
    for (int i = 0; i < 8; ++i)
#pragma unroll
        for (int jj = 0; jj < 4; ++jj) acc[i][jj] = 0.0f;

    float4 av0 = *(const float4*)&A[(l0 + ar0) * C_DIM + ac0];
    float4 av1 = *(const float4*)&A[(l0 + ar1) * C_DIM + ac0];
    float4 bv  = *(const float4*)&Bsrc[bk * ldb + coff + bn];

    for (int k0 = 0; k0 < C_DIM; k0 += 16) {
        __syncthreads();
        As[ac0 + 0][ar0] = av0.x;
        As[ac0 + 1][ar0] = av0.y;
        As[ac0 + 2][ar0] = av0.z;
        As[ac0 + 3][ar0] = av0.w;
        As[ac0 + 0][ar1] = av1.x;
        As[ac0 + 1][ar1] = av1.y;
        As[ac0 + 2][ar1] = av1.z;
        As[ac0 + 3][ar1] = av1.w;
        *(float4*)&Bs[bk][bn] = bv;
        __syncthreads();
        if (k0 + 16 < C_DIM) {
            av0 = *(const float4*)&A[(l0 + ar0) * C_DIM + (k0 + 16) + ac0];
            av1 = *(const float4*)&A[(l0 + ar1) * C_DIM + (k0 + 16) + ac0];
            bv  = *(const float4*)&Bsrc[(k0 + 16 + bk) * ldb + coff + bn];
        }
#pragma unroll
        for (int kk = 0; kk < 16; ++kk) {
            const float4 a4lo = *(const float4*)&As[kk][ty * 8];
            const float4 a4hi = *(const float4*)&As[kk][ty * 8 + 4];
            const float4 b4   = *(const float4*)&Bs[kk][tx * 4];
            const float ar[8] = {a4lo.x, a4lo.y, a4lo.z, a4lo.w,
                                 a4hi.x, a4hi.y, a4hi.z, a4hi.w};
            const float br[4] = {b4.x, b4.y, b4.z, b4.w};
#pragma unroll
            for (int i = 0; i < 8; ++i)
#pragma unroll
                for (int jj = 0; jj < 4; ++jj)
                    acc[i][jj] = fmaf(ar[i], br[jj], acc[i][jj]);
        }
    }

    const int g0 = n0 + tx * 4;
    float4 bz;
    float* dst;
    int stride, col;
    if (g0 < 512) { bz = *(const float4*)&kb[g0];       dst = kwbuf; stride = 512; col = g0; }
    else          { bz = *(const float4*)&vb[g0 - 512]; dst = vbuf;  stride = 256; col = g0 - 512; }
#pragma unroll
    for (int i = 0; i < 8; ++i) {
        const int row = l0 + ty * 8 + i;
        float4 o;
        o.x = acc[i][0] + bz.x;
        o.y = acc[i][1] + bz.y;
        o.z = acc[i][2] + bz.z;
        o.w = acc[i][3] + bz.w;
        *(float4*)&dst[row * stride + col] = o;
    }
}

// ================= K2: fused norm + small-proj + adaptive local conv =================
// Round-7 256-thread version verbatim (fast combined-weight path) + launch bounds.
__global__ void __launch_bounds__(256, 2)
conv_fused(const float* __restrict__ x,
           const float* __restrict__ ww, const float* __restrict__ wb,
           const float* __restrict__ wg,
           const float* __restrict__ ow, const float* __restrict__ ob,
           const float* __restrict__ og,
           const float* __restrict__ kg,
           const float* __restrict__ kwraw, const float* __restrict__ v,
           float* __restrict__ out) {
    const int l = blockIdx.x;
    const int tid = threadIdx.x;

    __shared__ float red[256];
    __shared__ float rs_s;
    __shared__ float kwrow[HK];
    __shared__ float wsz[H_HEADS], ofs[H_HEADS];
    __shared__ float4 tap[H_HEADS][N_OFF];      // {attn, frac, as_float(offF), as_float(offC)}
    __shared__ float2 warr[H_HEADS][N_OFF + 1]; // {combined weight, as_float(rowoff)}
    __shared__ float inv_denom[H_HEADS];
    __shared__ int okflag;

    if (tid == 0) okflag = 1;

    // ---- Phase A: rmsnorm(512) + silu ----
    {
        const int j = tid;
        const float* row = kwraw + l * HK;
        const float z0 = row[j];
        const float z1 = row[j + 256];
        red[j] = z0 * z0 + z1 * z1;
        __syncthreads();
        for (int s = 128; s > 0; s >>= 1) {
            if (j < s) red[j] += red[j + s];
            __syncthreads();
        }
        if (j == 0) rs_s = rsqrtf(red[0] / (float)HK + 1e-6f);
        __syncthreads();
        const float rs = rs_s;
        const float n0v = kg[j] * z0 * rs;
        const float n1v = kg[j + 256] * z1 * rs;
        kwrow[j]       = n0v * sigmoidf_(n0v);
        kwrow[j + 256] = n1v * sigmoidf_(n1v);
    }

    // ---- Phase B: small projections (wave 0); 8-lane parallel tail ----
    if (tid < 64) {
        const int lane = tid;
        const float* xr = x + l * C_DIM;
        float accw[H_HEADS], acco[H_HEADS];
#pragma unroll
        for (int h = 0; h < H_HEADS; ++h) { accw[h] = 0.0f; acco[h] = 0.0f; }
#pragma unroll
        for (int i = 0; i < C_DIM / 64; ++i) {
            const int c = lane + i * 64;
            const float xv = xr[c];
            const float* wwc = ww + c * H_HEADS;
            const float* owc = ow + c * H_HEADS;
#pragma unroll
            for (int h = 0; h < H_HEADS; ++h) {
                accw[h] = fmaf(xv, wwc[h], accw[h]);
                acco[h] = fmaf(xv, owc[h], acco[h]);
            }
        }
#pragma unroll
        for (int off = 32; off > 0; off >>= 1) {
#pragma unroll
            for (int h = 0; h < H_HEADS; ++h) {
                accw[h] += __shfl_xor(accw[h], off);
                acco[h] += __shfl_xor(acco[h], off);
            }
        }
        if (lane < H_HEADS) {
            float zw[H_HEADS], zo[H_HEADS];
            float ssw = 0.0f, sso = 0.0f;
#pragma unroll
            for (int h = 0; h < H_HEADS; ++h) {
                zw[h] = accw[h] + wb[h];
                zo[h] = acco[h] + ob[h];
                ssw += zw[h] * zw[h];
                sso += zo[h] * zo[h];
            }
            const float rw = rsqrtf(ssw / (float)H_HEADS + 1e-6f);
            const float ro = rsqrtf(sso / (float)H_HEADS + 1e-6f);
            const float nw = wg[lane] * zw[lane] * rw;
            const float no = og[lane] * zo[lane] * ro;
            wsz[lane] = 1.0f + sigmoidf_(nw) * 63.0f;
            ofs[lane] = tanhf(no) * 64.0f;
        }
    }
    __syncthreads();

    // ---- Stage 1: attention taps ----
    for (int t = tid; t < H_HEADS * N_OFF; t += 256) {
        const int h = t / N_OFF;
        const int n = t - h * N_OFF;
        const float ws  = wsz[h];
        const float off = ofs[h];
        const float local = (float)(n - HALF_W);
        const float neighbor = (float)l + off + local;
        const bool valid = (neighbor >= 0.0f) && (neighbor < (float)L_SEQ);
        const float nc = fminf(fmaxf(neighbor, 0.0f), (float)(L_SEQ - 1));

        const float rel = fabsf(local) / (ws * 0.5f + 1e-6f);
        const float mask = sigmoidf_(5.0f * (1.0f - rel)) * (valid ? 1.0f : 0.0f);

        const float kidx = fminf(rel, 1.0f) * (float)(K_MAX - 1);
        int ifl = (int)kidx;
        ifl = min(ifl, K_MAX - 2);
        const float wce = kidx - (float)ifl;
        const float kf = kwrow[h * K_MAX + ifl];
        const float kc = kwrow[h * K_MAX + ifl + 1];
        const float attnv = (kf * (1.0f - wce) + kc * wce) * mask;

        int p = (int)floorf(nc);
        p = min(max(p, 0), L_SEQ - 1);
        const int pc = min(p + 1, L_SEQ - 1);
        const float fr = nc - (float)p;

        float4 tv;
        tv.x = attnv;
        tv.y = fr;
        tv.z = __int_as_float(p * C_DIM + h * D_HEAD);
        tv.w = __int_as_float(pc * C_DIM + h * D_HEAD);
        tap[h][n] = tv;
    }
    __syncthreads();

    // ---- Stage 1.5: combined row weights + fast-path validity ----
    for (int t = tid; t < H_HEADS * (N_OFF + 1); t += 256) {
        const int h = t / (N_OFF + 1);
        const int m = t - h * (N_OFF + 1);
        float w, rowf;
        if (m == 0) {
            const float4 cur = tap[h][0];
            w = cur.x * (1.0f - cur.y);
            rowf = cur.z;
        } else {
            const float4 prev = tap[h][m - 1];
            const float wc = prev.x * prev.y;
            if (m < N_OFF) {
                const float4 cur = tap[h][m];
                w = cur.x * (1.0f - cur.y) + wc;
                rowf = cur.z;
                if (wc != 0.0f && __float_as_int(prev.w) != __float_as_int(cur.z))
                    okflag = 0;   // benign race: all writers store 0
            } else {
                w = wc;
                rowf = prev.w;
            }
        }
        warr[h][m] = make_float2(w, rowf);
    }

    // ---- Stage 2: per-head denominators (serial n order) ----
    if (tid < H_HEADS) {
        float s = 0.0f;
        for (int n = 0; n < N_OFF; ++n) s += tap[tid][n].x;
        inv_denom[tid] = 1.0f / (s + 1e-6f);
    }
    __syncthreads();

    // ---- Stage 3: gather & accumulate ----
    const int h = tid >> 5;
    const int d = tid & 31;
    float acc = 0.0f;
    if (okflag) {
#pragma unroll 6
        for (int m = 0; m < N_OFF + 1; ++m) {
            const float2 t2 = warr[h][m];
            acc = fmaf(t2.x, v[__float_as_int(t2.y) + d], acc);
        }
    } else {
#pragma unroll 5
        for (int n = 0; n < N_OFF; ++n) {
            const float4 t4 = tap[h][n];
            const int bf = __float_as_int(t4.z);
            const int bc = __float_as_int(t4.w);
            const float vf = v[bf + d];
            const float vc = v[bc + d];
            acc = fmaf(t4.x, fmaf(t4.y, vc - vf, vf), acc);
        }
    }
    out[l * C_DIM + h * D_HEAD + d] = acc * inv_denom[h];
}

// ================= K3: out projection GEMM + silu =================
// BM=64, BN=64, BK=16, TM=4, TN=4, 256 threads, grid (4, 64) = 256 blocks.
__global__ void __launch_bounds__(256, 4)
out_gemm(const float* __restrict__ A, const float* __restrict__ W,
         float* __restrict__ out) {
    __shared__ float As[16][68];
    __shared__ float Bs[16][68];

    const int tid = threadIdx.x;
    const int tx = tid & 15;
    const int ty = tid >> 4;
    const int l0 = blockIdx.y * 64;
    const int n0 = blockIdx.x * 64;

    const int am = tid >> 2;
    const int ak = (tid & 3) * 4;
    const int bk = tid >> 4;
    const int bn = (tid & 15) * 4;

    float acc[4][4];
#pragma unroll
    for (int i = 0; i < 4; ++i)
#pragma unroll
        for (int jj = 0; jj < 4; ++jj) acc[i][jj] = 0.0f;

    float4 av = *(const float4*)&A[(l0 + am) * C_DIM + ak];
    float4 bv = *(const float4*)&W[bk * C_DIM + n0 + bn];

    for (int k0 = 0; k0 < C_DIM; k0 += 16) {
        __syncthreads();
        As[ak + 0][am] = av.x;
        As[ak + 1][am] = av.y;
        As[ak + 2][am] = av.z;
        As[ak + 3][am] = av.w;
        *(float4*)&Bs[bk][bn] = bv;
        __syncthreads();
        if (k0 + 16 < C_DIM) {
            av = *(const float4*)&A[(l0 + am) * C_DIM + (k0 + 16) + ak];
            bv = *(const float4*)&W[(k0 + 16 + bk) * C_DIM + n0 + bn];
        }
#pragma unroll
        for (int kk = 0; kk < 16; ++kk) {
            const float4 a4 = *(const float4*)&As[kk][ty * 4];
            const float4 b4 = *(const float4*)&Bs[kk][tx * 4];
            const float ar[4] = {a4.x, a4.y, a4.z, a4.w};
            const float br[4] = {b4.x, b4.y, b4.z, b4.w};
#pragma unroll
            for (int i = 0; i < 4; ++i)
#pragma unroll
                for (int jj = 0; jj < 4; ++jj)
                    acc[i][jj] = fmaf(ar[i], br[jj], acc[i][jj]);
        }
    }

    const int g0 = n0 + tx * 4;
#pragma unroll
    for (int i = 0; i < 4; ++i) {
        const int row = l0 + ty * 4 + i;
        float4 o;
        o.x = acc[i][0] * sigmoidf_(acc[i][0]);
        o.y = acc[i][1] * sigmoidf_(acc[i][1]);
        o.z = acc[i][2] * sigmoidf_(acc[i][2]);
        o.w = acc[i][3] * sigmoidf_(acc[i][3]);
        *(float4*)&out[row * C_DIM + g0] = o;
    }
}

extern "C" void kernel_launch(void* const* d_in, const int* in_sizes, int n_in,
                              void* d_out, int out_size, void* d_ws, size_t ws_size,
                              hipStream_t stream) {
    const float* x    = (const float*)d_in[0];
    const float* ww   = (const float*)d_in[1];
    const float* wb   = (const float*)d_in[2];
    const float* wg   = (const float*)d_in[3];
    const float* ow   = (const float*)d_in[4];
    const float* ob   = (const float*)d_in[5];
    const float* og   = (const float*)d_in[6];
    const float* kw_w = (const float*)d_in[7];
    const float* kb   = (const float*)d_in[8];
    const float* kg   = (const float*)d_in[9];
    const float* vw   = (const float*)d_in[10];
    const float* vb   = (const float*)d_in[11];
    const float* outw = (const float*)d_in[12];
    float* y = (float*)d_out;

    float* ws_f    = (float*)d_ws;
    float* kwbuf   = ws_f;                       // 4096*512 (raw z+bias)
    float* vbuf    = kwbuf + L_SEQ * HK;         // 4096*256
    float* convbuf = vbuf + L_SEQ * C_DIM;       // 4096*256

    proj_gemm<<<dim3(12, L_SEQ / 128), 256, 0, stream>>>(x, kw_w, vw, kb, vb, kwbuf, vbuf);
    conv_fused<<<L_SEQ, 256, 0, stream>>>(x, ww, wb, wg, ow, ob, og, kg, kwbuf, vbuf, convbuf);
    out_gemm<<<dim3(C_DIM / 64, L_SEQ / 64), 256, 0, stream>>>(convbuf, outw, y);
}